// Round 13
// baseline (274.746 us; speedup 1.0000x reference)
//
#include <hip/hip_runtime.h>
#include <cmath>

#define NODES 40000
#define EDGES 600000
#define HD    128
#define CAP   80            // bucket capacity (Poisson mean 15; P(>80) ~ 0)
#define BN_EPS 1e-5f

typedef short bf16x8 __attribute__((ext_vector_type(8)));
typedef float f32x4  __attribute__((ext_vector_type(4)));
typedef unsigned int u32x2 __attribute__((ext_vector_type(2)));  // clang-native
typedef unsigned short u16;
typedef unsigned int   u32;

__device__ __forceinline__ float bf2f(u16 u) {
  union { u32 i; float f; } v; v.i = ((u32)u) << 16; return v.f;
}
__device__ __forceinline__ u16 f2bf(float f) {
  union { float f; u32 i; } v; v.f = f;
  u32 r = v.i + 0x7FFF + ((v.i >> 16) & 1);   // RNE
  return (u16)(r >> 16);
}
// ELU via hardware exp (v_exp_f32): ~5 VALU insts vs ~45 for expm1f.
__device__ __forceinline__ float elu(float x) {
  return x > 0.f ? x : __expf(x) - 1.f;
}

struct WPrep { const float* s[8]; u16* d[8]; };

// ---------------- one-time prep: cast x | transpose weights | zero cnt -----
__global__ __launch_bounds__(256) void prep_all(const float4* __restrict__ x4,
                                                ushort4* __restrict__ xb4,
                                                WPrep p, int* __restrict__ cnt) {
  const int bid = blockIdx.x;
  const int tid = threadIdx.x;
  if (bid < 5000) {
    int i = bid * 256 + tid;
    float4 v = x4[i];
    ushort4 o;
    o.x = f2bf(v.x); o.y = f2bf(v.y); o.z = f2bf(v.z); o.w = f2bf(v.w);
    xb4[i] = o;
  } else if (bid < 5128) {
    int b = bid - 5000;
    int m = b >> 4, xx = b & 15;
    int N = (m == 7) ? 64 : 128;
    int tiles_n = N / 32;
    int tx = xx % tiles_n, tk = xx / tiles_n;
    if (tk >= 4) return;
    __shared__ float t[32][33];
    int c = tid & 31, r8 = tid >> 5;
    const float* s = p.s[m];
    for (int rr = 0; rr < 32; rr += 8)
      t[rr + r8][c] = s[(size_t)(tk * 32 + rr + r8) * N + tx * 32 + c];
    __syncthreads();
    u16* d = p.d[m];
    for (int rr = 0; rr < 32; rr += 8)
      d[(size_t)(tx * 32 + rr + r8) * HD + tk * 32 + c] = f2bf(t[c][rr + r8]);
  } else {
    int i = (bid - 5128) * 256 + tid;
    if (i < NODES) cnt[i] = 0;
  }
}

// ---------------- bucket fill ----------------
__global__ __launch_bounds__(256) void bucket_fill(const int* __restrict__ ei,
                                                   int* __restrict__ cnt,
                                                   int* __restrict__ bucket) {
  int e = blockIdx.x * 256 + threadIdx.x;
  if (e >= EDGES) return;
  int s = ei[e];
  int d = ei[EDGES + e];
  int pos = atomicAdd(&cnt[d], 1);
  if (pos < CAP) bucket[d * CAP + pos] = s;
}

// -------- gather: agg = x[i] + sum x[src]; 16-deep load pipeline -----------
// half-wave (32 lanes x 8B) per node. Slot chunk loaded once per half-wave,
// broadcast via __shfl; 16 row-loads issued before any accumulate (one vmcnt
// round covers the mean degree of 15). agg stores nontemporal.
__global__ __launch_bounds__(256) void gather_w(const u16* __restrict__ x,
                                                const int* __restrict__ cnt,
                                                const int* __restrict__ bucket,
                                                u16* __restrict__ agg) {
  const int tid = threadIdx.x;
  const int half = (tid >> 5) & 1;
  const int hl = tid & 31;
  const int node = blockIdx.x * 8 + (tid >> 6) * 2 + half;

  u32x2 self = ((const u32x2*)(x + (size_t)node * HD))[hl];
  float a0 = bf2f((u16)self.x), a1 = bf2f((u16)(self.x >> 16));
  float a2 = bf2f((u16)self.y), a3 = bf2f((u16)(self.y >> 16));
  int deg = cnt[node];
  if (deg > CAP) deg = CAP;
  const int i0 = node * CAP;

  for (int c0 = 0; c0 < deg; c0 += 32) {
    int m = deg - c0;
    if (m > 32) m = 32;
    // lanes >= m load a valid duplicate (entry 0 of this node)
    int sv = bucket[i0 + (hl < m ? c0 + hl : 0)];
    for (int j = 0; j < m; j += 16) {
      int idx[16];
      u32x2 uu[16];
#pragma unroll
      for (int jj = 0; jj < 16; ++jj) {
        int src = j + jj < m ? j + jj : 0;
        idx[jj] = __shfl(sv, src, 32);
      }
#pragma unroll
      for (int jj = 0; jj < 16; ++jj)
        uu[jj] = ((const u32x2*)(x + (size_t)idx[jj] * HD))[hl];
#pragma unroll
      for (int jj = 0; jj < 16; ++jj) {
        if (j + jj < m) {
          a0 += bf2f((u16)uu[jj].x);
          a1 += bf2f((u16)(uu[jj].x >> 16));
          a2 += bf2f((u16)uu[jj].y);
          a3 += bf2f((u16)(uu[jj].y >> 16));
        }
      }
    }
  }
  u32x2 pk;
  pk.x = (u32)f2bf(a0) | ((u32)f2bf(a1) << 16);
  pk.y = (u32)f2bf(a2) | ((u32)f2bf(a3) << 16);
  // streamed output, consumed once by the next MLP: don't pollute L2
  __builtin_nontemporal_store(pk, (u32x2*)(agg + (size_t)node * HD) + hl);
}

// ---------------- fused MLP (layers 1-2) ----------------
// ELU(BN(A@W1+b1)) @ W2 + b2, ELU -> bf16 out.
// LDS rows 0-127: weight (W1, then W2 re-staged); rows 128-191: H strips.
__global__ __launch_bounds__(256) void mlp_fused(
    const u16* __restrict__ A, const u16* __restrict__ W1t,
    const float* __restrict__ b1, const float* __restrict__ g,
    const float* __restrict__ bt, const float* __restrict__ mu,
    const float* __restrict__ vr, const u16* __restrict__ W2t,
    const float* __restrict__ b2, u16* __restrict__ out) {
  constexpr int PK = HD + 8;
  __shared__ u16 L[192][PK];   // 52224 B -> 3 blocks/CU

  const int tid = threadIdx.x;
  const int wv = tid >> 6, lane = tid & 63;
  const int col = lane & 15, kg = lane >> 4;

#pragma unroll
  for (int t = tid; t < 128 * 16; t += 256) {
    int r = t >> 4, c8 = t & 15;
    *(bf16x8*)&L[r][c8 * 8] = *(const bf16x8*)(W1t + (size_t)r * HD + c8 * 8);
  }
  __syncthreads();

  const int strip = blockIdx.x * 4 + wv;
  const u16* Arow = A + (size_t)(strip * 16 + col) * HD;
  const int hrow = 128 + wv * 16;

  // GEMM1
  f32x4 acc[8];
#pragma unroll
  for (int t = 0; t < 8; ++t) acc[t] = (f32x4){0.f, 0.f, 0.f, 0.f};
#pragma unroll
  for (int kk = 0; kk < HD; kk += 32) {
    bf16x8 av = *(const bf16x8*)(Arow + kk + kg * 8);
#pragma unroll
    for (int t = 0; t < 8; ++t) {
      bf16x8 bv = *(const bf16x8*)&L[t * 16 + col][kk + kg * 8];
      acc[t] = __builtin_amdgcn_mfma_f32_16x16x32_bf16(av, bv, acc[t], 0, 0, 0);
    }
  }
  __syncthreads();  // all waves done reading W1

  // stage W2 into rows 0-127; write H (BN+ELU) into own strip
#pragma unroll
  for (int t = tid; t < 128 * 16; t += 256) {
    int r = t >> 4, c8 = t & 15;
    *(bf16x8*)&L[r][c8 * 8] = *(const bf16x8*)(W2t + (size_t)r * HD + c8 * 8);
  }
#pragma unroll
  for (int t = 0; t < 8; ++t) {
    int c = t * 16 + col;
    float rs = rsqrtf(vr[c] + BN_EPS) * g[c];
    float bb = bt[c] + (b1[c] - mu[c]) * rs;
#pragma unroll
    for (int r = 0; r < 4; ++r)
      L[hrow + kg * 4 + r][c] = f2bf(elu(acc[t][r] * rs + bb));
  }
  __syncthreads();

  // GEMM2
  f32x4 acc2[8];
#pragma unroll
  for (int t = 0; t < 8; ++t) acc2[t] = (f32x4){0.f, 0.f, 0.f, 0.f};
#pragma unroll
  for (int kk = 0; kk < HD; kk += 32) {
    bf16x8 av = *(const bf16x8*)&L[hrow + col][kk + kg * 8];
#pragma unroll
    for (int t = 0; t < 8; ++t) {
      bf16x8 bv = *(const bf16x8*)&L[t * 16 + col][kk + kg * 8];
      acc2[t] = __builtin_amdgcn_mfma_f32_16x16x32_bf16(av, bv, acc2[t], 0, 0, 0);
    }
  }
#pragma unroll
  for (int t = 0; t < 8; ++t) {
    int c = t * 16 + col;
    float bb = b2[c];
#pragma unroll
    for (int r = 0; r < 4; ++r)
      L[hrow + kg * 4 + r][c] = f2bf(elu(acc2[t][r] + bb));
  }
  {
    int r0 = lane >> 4, seg = lane & 15;
#pragma unroll
    for (int rr = 0; rr < 16; rr += 4) {
      int row = rr + r0;
      *(float4*)((char*)(out + (size_t)(strip * 16 + row) * HD) + seg * 16) =
          *(const float4*)((const char*)&L[hrow + row][0] + seg * 16);
    }
  }
}

// ------- layer-3 MLP + head: 4 chained GEMMs, all B staged in LDS ----------
__global__ __launch_bounds__(256) void mlp3_head(
    const u16* __restrict__ A, const u16* __restrict__ W1t,
    const float* __restrict__ b1, const float* __restrict__ g,
    const float* __restrict__ bt, const float* __restrict__ mu,
    const float* __restrict__ vr, const u16* __restrict__ W2t,
    const float* __restrict__ b2, const u16* __restrict__ L1t,
    const float* __restrict__ lb1, const u16* __restrict__ L2t,
    const float* __restrict__ lb2, float* __restrict__ out) {
  constexpr int PK = HD + 8;
  __shared__ u16 L[192][PK];

  const int tid = threadIdx.x;
  const int wv = tid >> 6, lane = tid & 63;
  const int col = lane & 15, kg = lane >> 4;

#pragma unroll
  for (int t = tid; t < 128 * 16; t += 256) {
    int r = t >> 4, c8 = t & 15;
    *(bf16x8*)&L[r][c8 * 8] = *(const bf16x8*)(W1t + (size_t)r * HD + c8 * 8);
  }
  __syncthreads();

  const int strip = blockIdx.x * 4 + wv;
  const u16* Arow = A + (size_t)(strip * 16 + col) * HD;
  const int hrow = 128 + wv * 16;

  // GEMM1 (BN+ELU)
  f32x4 acc[8];
#pragma unroll
  for (int t = 0; t < 8; ++t) acc[t] = (f32x4){0.f, 0.f, 0.f, 0.f};
#pragma unroll
  for (int kk = 0; kk < HD; kk += 32) {
    bf16x8 av = *(const bf16x8*)(Arow + kk + kg * 8);
#pragma unroll
    for (int t = 0; t < 8; ++t) {
      bf16x8 bv = *(const bf16x8*)&L[t * 16 + col][kk + kg * 8];
      acc[t] = __builtin_amdgcn_mfma_f32_16x16x32_bf16(av, bv, acc[t], 0, 0, 0);
    }
  }
  __syncthreads();
#pragma unroll
  for (int t = tid; t < 128 * 16; t += 256) {   // stage W2
    int r = t >> 4, c8 = t & 15;
    *(bf16x8*)&L[r][c8 * 8] = *(const bf16x8*)(W2t + (size_t)r * HD + c8 * 8);
  }
#pragma unroll
  for (int t = 0; t < 8; ++t) {
    int c = t * 16 + col;
    float rs = rsqrtf(vr[c] + BN_EPS) * g[c];
    float bb = bt[c] + (b1[c] - mu[c]) * rs;
#pragma unroll
    for (int r = 0; r < 4; ++r)
      L[hrow + kg * 4 + r][c] = f2bf(elu(acc[t][r] * rs + bb));
  }
  __syncthreads();

  // GEMM2 (+b2, ELU)
#pragma unroll
  for (int t = 0; t < 8; ++t) acc[t] = (f32x4){0.f, 0.f, 0.f, 0.f};
#pragma unroll
  for (int kk = 0; kk < HD; kk += 32) {
    bf16x8 av = *(const bf16x8*)&L[hrow + col][kk + kg * 8];
#pragma unroll
    for (int t = 0; t < 8; ++t) {
      bf16x8 bv = *(const bf16x8*)&L[t * 16 + col][kk + kg * 8];
      acc[t] = __builtin_amdgcn_mfma_f32_16x16x32_bf16(av, bv, acc[t], 0, 0, 0);
    }
  }
  __syncthreads();
#pragma unroll
  for (int t = tid; t < 128 * 16; t += 256) {   // stage lin1
    int r = t >> 4, c8 = t & 15;
    *(bf16x8*)&L[r][c8 * 8] = *(const bf16x8*)(L1t + (size_t)r * HD + c8 * 8);
  }
#pragma unroll
  for (int t = 0; t < 8; ++t) {
    int c = t * 16 + col;
    float bb = b2[c];
#pragma unroll
    for (int r = 0; r < 4; ++r)
      L[hrow + kg * 4 + r][c] = f2bf(elu(acc[t][r] + bb));
  }
  __syncthreads();

  // LIN1 (+lb1, ELU)
#pragma unroll
  for (int t = 0; t < 8; ++t) acc[t] = (f32x4){0.f, 0.f, 0.f, 0.f};
#pragma unroll
  for (int kk = 0; kk < HD; kk += 32) {
    bf16x8 av = *(const bf16x8*)&L[hrow + col][kk + kg * 8];
#pragma unroll
    for (int t = 0; t < 8; ++t) {
      bf16x8 bv = *(const bf16x8*)&L[t * 16 + col][kk + kg * 8];
      acc[t] = __builtin_amdgcn_mfma_f32_16x16x32_bf16(av, bv, acc[t], 0, 0, 0);
    }
  }
  __syncthreads();
#pragma unroll
  for (int t = tid; t < 64 * 16; t += 256) {    // stage lin2 (64 rows)
    int r = t >> 4, c8 = t & 15;
    *(bf16x8*)&L[r][c8 * 8] = *(const bf16x8*)(L2t + (size_t)r * HD + c8 * 8);
  }
#pragma unroll
  for (int t = 0; t < 8; ++t) {
    int c = t * 16 + col;
    float bb = lb1[c];
#pragma unroll
    for (int r = 0; r < 4; ++r)
      L[hrow + kg * 4 + r][c] = f2bf(elu(acc[t][r] + bb));
  }
  __syncthreads();

  // LIN2 (+lb2) -> fp32 out [.][64]
  f32x4 acc2[4];
#pragma unroll
  for (int t = 0; t < 4; ++t) acc2[t] = (f32x4){0.f, 0.f, 0.f, 0.f};
#pragma unroll
  for (int kk = 0; kk < HD; kk += 32) {
    bf16x8 av = *(const bf16x8*)&L[hrow + col][kk + kg * 8];
#pragma unroll
    for (int t = 0; t < 4; ++t) {
      bf16x8 bv = *(const bf16x8*)&L[t * 16 + col][kk + kg * 8];
      acc2[t] = __builtin_amdgcn_mfma_f32_16x16x32_bf16(av, bv, acc2[t], 0, 0, 0);
    }
  }
#pragma unroll
  for (int t = 0; t < 4; ++t) {
    int c = t * 16 + col;
    float bb = lb2[c];
#pragma unroll
    for (int r = 0; r < 4; ++r)
      ((float*)&L[hrow + kg * 4 + r][0])[c] = acc2[t][r] + bb;
  }
  {
    int r0 = lane >> 4, seg = lane & 15;
#pragma unroll
    for (int rr = 0; rr < 16; rr += 4) {
      int row = rr + r0;
      *(float4*)((char*)(out + (size_t)(strip * 16 + row) * 64) + seg * 16) =
          *(const float4*)((const char*)&L[hrow + row][0] + seg * 16);
    }
  }
}

extern "C" void kernel_launch(void* const* d_in, const int* in_sizes, int n_in,
                              void* d_out, int out_size, void* d_ws, size_t ws_size,
                              hipStream_t stream) {
  const float* x = (const float*)d_in[0];
  const int* ei  = (const int*)d_in[1];
  const float* p[30];
  for (int i = 0; i < 30 && i < n_in; ++i) p[i] = (const float*)d_in[i];

  const size_t FEAT = (size_t)NODES * HD;
  u16* xb   = (u16*)d_ws;
  u16* tmp  = xb + FEAT;
  u16* wt   = tmp + FEAT;
  u16* wts[8];
  for (int m = 0; m < 8; ++m) wts[m] = wt + (size_t)m * HD * HD;
  int* cnt    = (int*)(wt + 8 * HD * HD);
  int* bucket = cnt + NODES;

  dim3 blk(256);
  const int edgeGrid = (EDGES + 255) / 256;   // 2344
  const int gathGrid = NODES / 8;             // 5000
  const int gemmGrid = NODES / 64;            // 625

  WPrep wp;
  const int widx[8] = {2, 8, 10, 16, 18, 24, 26, 28};
  for (int m = 0; m < 8; ++m) { wp.s[m] = p[widx[m]]; wp.d[m] = wts[m]; }
  prep_all<<<5285, blk, 0, stream>>>((const float4*)x, (ushort4*)xb, wp, cnt);
  bucket_fill<<<edgeGrid, blk, 0, stream>>>(ei, cnt, bucket);

  for (int l = 0; l < 2; ++l) {
    const int base = 2 + l * 8;
    gather_w<<<gathGrid, blk, 0, stream>>>(xb, cnt, bucket, tmp);
    mlp_fused<<<gemmGrid, blk, 0, stream>>>(
        tmp, wts[l * 2], p[base + 1], p[base + 2], p[base + 3], p[base + 4],
        p[base + 5], wts[l * 2 + 1], p[base + 7], xb);
  }
  gather_w<<<gathGrid, blk, 0, stream>>>(xb, cnt, bucket, tmp);
  mlp3_head<<<gemmGrid, blk, 0, stream>>>(
      tmp, wts[4], p[19], p[20], p[21], p[22], p[23], wts[5], p[25],
      wts[6], p[27], wts[7], p[29], (float*)d_out);
}

// Round 14
// 265.714 us; speedup vs baseline: 1.0340x; 1.0340x over previous
//
#include <hip/hip_runtime.h>
#include <cmath>

#define NODES 40000
#define EDGES 600000
#define HD    128
#define CAP   80            // bucket capacity (Poisson mean 15; P(>80) ~ 0)
#define BN_EPS 1e-5f

typedef short bf16x8 __attribute__((ext_vector_type(8)));
typedef float f32x4  __attribute__((ext_vector_type(4)));
typedef unsigned short u16;
typedef unsigned int   u32;

__device__ __forceinline__ float bf2f(u16 u) {
  union { u32 i; float f; } v; v.i = ((u32)u) << 16; return v.f;
}
__device__ __forceinline__ u16 f2bf(float f) {
  union { float f; u32 i; } v; v.f = f;
  u32 r = v.i + 0x7FFF + ((v.i >> 16) & 1);   // RNE
  return (u16)(r >> 16);
}
// ELU via hardware exp (v_exp_f32): ~5 VALU insts vs ~45 for expm1f.
__device__ __forceinline__ float elu(float x) {
  return x > 0.f ? x : __expf(x) - 1.f;
}

struct WPrep { const float* s[8]; u16* d[8]; };

// ---------------- one-time prep: cast x | transpose weights | zero cnt -----
__global__ __launch_bounds__(256) void prep_all(const float4* __restrict__ x4,
                                                ushort4* __restrict__ xb4,
                                                WPrep p, int* __restrict__ cnt) {
  const int bid = blockIdx.x;
  const int tid = threadIdx.x;
  if (bid < 5000) {
    int i = bid * 256 + tid;
    float4 v = x4[i];
    ushort4 o;
    o.x = f2bf(v.x); o.y = f2bf(v.y); o.z = f2bf(v.z); o.w = f2bf(v.w);
    xb4[i] = o;
  } else if (bid < 5128) {
    int b = bid - 5000;
    int m = b >> 4, xx = b & 15;
    int N = (m == 7) ? 64 : 128;
    int tiles_n = N / 32;
    int tx = xx % tiles_n, tk = xx / tiles_n;
    if (tk >= 4) return;
    __shared__ float t[32][33];
    int c = tid & 31, r8 = tid >> 5;
    const float* s = p.s[m];
    for (int rr = 0; rr < 32; rr += 8)
      t[rr + r8][c] = s[(size_t)(tk * 32 + rr + r8) * N + tx * 32 + c];
    __syncthreads();
    u16* d = p.d[m];
    for (int rr = 0; rr < 32; rr += 8)
      d[(size_t)(tx * 32 + rr + r8) * HD + tk * 32 + c] = f2bf(t[c][rr + r8]);
  } else {
    int i = (bid - 5128) * 256 + tid;
    if (i < NODES) cnt[i] = 0;
  }
}

// ---------------- bucket fill ----------------
__global__ __launch_bounds__(256) void bucket_fill(const int* __restrict__ ei,
                                                   int* __restrict__ cnt,
                                                   int* __restrict__ bucket) {
  int e = blockIdx.x * 256 + threadIdx.x;
  if (e >= EDGES) return;
  int s = ei[e];
  int d = ei[EDGES + e];
  int pos = atomicAdd(&cnt[d], 1);
  if (pos < CAP) bucket[d * CAP + pos] = s;
}

// -------- gather: agg = x[i] + sum x[src]; slot indices shfl-broadcast -----
// half-wave (32 lanes x uint2 = 256B) per node. Each half-wave loads its
// 32-entry slot chunk ONCE (1 load/lane) and broadcasts via __shfl(.,.,32).
// 8-deep load pipeline (R11-proven; 16-deep regressed, R13).
__global__ __launch_bounds__(256) void gather_w(const u16* __restrict__ x,
                                                const int* __restrict__ cnt,
                                                const int* __restrict__ bucket,
                                                u16* __restrict__ agg) {
  const int tid = threadIdx.x;
  const int half = (tid >> 5) & 1;
  const int hl = tid & 31;
  const int node = blockIdx.x * 8 + (tid >> 6) * 2 + half;

  uint2 self = ((const uint2*)(x + (size_t)node * HD))[hl];
  float a0 = bf2f((u16)self.x), a1 = bf2f((u16)(self.x >> 16));
  float a2 = bf2f((u16)self.y), a3 = bf2f((u16)(self.y >> 16));
  int deg = cnt[node];
  if (deg > CAP) deg = CAP;
  const int i0 = node * CAP;

  for (int c0 = 0; c0 < deg; c0 += 32) {
    int m = deg - c0;
    if (m > 32) m = 32;
    // lanes >= m load a valid duplicate (entry 0 of this node)
    int sv = bucket[i0 + (hl < m ? c0 + hl : 0)];
    for (int j = 0; j < m; j += 8) {
      int idx[8];
      uint2 uu[8];
#pragma unroll
      for (int jj = 0; jj < 8; ++jj) {
        int src = j + jj < m ? j + jj : 0;
        idx[jj] = __shfl(sv, src, 32);
      }
#pragma unroll
      for (int jj = 0; jj < 8; ++jj)
        uu[jj] = ((const uint2*)(x + (size_t)idx[jj] * HD))[hl];
#pragma unroll
      for (int jj = 0; jj < 8; ++jj) {
        if (j + jj < m) {
          a0 += bf2f((u16)uu[jj].x);
          a1 += bf2f((u16)(uu[jj].x >> 16));
          a2 += bf2f((u16)uu[jj].y);
          a3 += bf2f((u16)(uu[jj].y >> 16));
        }
      }
    }
  }
  uint2 pk;
  pk.x = (u32)f2bf(a0) | ((u32)f2bf(a1) << 16);
  pk.y = (u32)f2bf(a2) | ((u32)f2bf(a3) << 16);
  ((uint2*)(agg + (size_t)node * HD))[hl] = pk;
}

// ---------------- fused MLP (layers 1-2) ----------------
// ELU(BN(A@W1+b1)) @ W2 + b2, ELU -> bf16 out.
// LDS rows 0-127: weight (W1, then W2 re-staged); rows 128-191: H strips.
__global__ __launch_bounds__(256) void mlp_fused(
    const u16* __restrict__ A, const u16* __restrict__ W1t,
    const float* __restrict__ b1, const float* __restrict__ g,
    const float* __restrict__ bt, const float* __restrict__ mu,
    const float* __restrict__ vr, const u16* __restrict__ W2t,
    const float* __restrict__ b2, u16* __restrict__ out) {
  constexpr int PK = HD + 8;
  __shared__ u16 L[192][PK];   // 52224 B -> 3 blocks/CU

  const int tid = threadIdx.x;
  const int wv = tid >> 6, lane = tid & 63;
  const int col = lane & 15, kg = lane >> 4;

#pragma unroll
  for (int t = tid; t < 128 * 16; t += 256) {
    int r = t >> 4, c8 = t & 15;
    *(bf16x8*)&L[r][c8 * 8] = *(const bf16x8*)(W1t + (size_t)r * HD + c8 * 8);
  }
  __syncthreads();

  const int strip = blockIdx.x * 4 + wv;
  const u16* Arow = A + (size_t)(strip * 16 + col) * HD;
  const int hrow = 128 + wv * 16;

  // GEMM1
  f32x4 acc[8];
#pragma unroll
  for (int t = 0; t < 8; ++t) acc[t] = (f32x4){0.f, 0.f, 0.f, 0.f};
#pragma unroll
  for (int kk = 0; kk < HD; kk += 32) {
    bf16x8 av = *(const bf16x8*)(Arow + kk + kg * 8);
#pragma unroll
    for (int t = 0; t < 8; ++t) {
      bf16x8 bv = *(const bf16x8*)&L[t * 16 + col][kk + kg * 8];
      acc[t] = __builtin_amdgcn_mfma_f32_16x16x32_bf16(av, bv, acc[t], 0, 0, 0);
    }
  }
  __syncthreads();  // all waves done reading W1

  // stage W2 into rows 0-127; write H (BN+ELU) into own strip
#pragma unroll
  for (int t = tid; t < 128 * 16; t += 256) {
    int r = t >> 4, c8 = t & 15;
    *(bf16x8*)&L[r][c8 * 8] = *(const bf16x8*)(W2t + (size_t)r * HD + c8 * 8);
  }
#pragma unroll
  for (int t = 0; t < 8; ++t) {
    int c = t * 16 + col;
    float rs = rsqrtf(vr[c] + BN_EPS) * g[c];
    float bb = bt[c] + (b1[c] - mu[c]) * rs;
#pragma unroll
    for (int r = 0; r < 4; ++r)
      L[hrow + kg * 4 + r][c] = f2bf(elu(acc[t][r] * rs + bb));
  }
  __syncthreads();

  // GEMM2
  f32x4 acc2[8];
#pragma unroll
  for (int t = 0; t < 8; ++t) acc2[t] = (f32x4){0.f, 0.f, 0.f, 0.f};
#pragma unroll
  for (int kk = 0; kk < HD; kk += 32) {
    bf16x8 av = *(const bf16x8*)&L[hrow + col][kk + kg * 8];
#pragma unroll
    for (int t = 0; t < 8; ++t) {
      bf16x8 bv = *(const bf16x8*)&L[t * 16 + col][kk + kg * 8];
      acc2[t] = __builtin_amdgcn_mfma_f32_16x16x32_bf16(av, bv, acc2[t], 0, 0, 0);
    }
  }
#pragma unroll
  for (int t = 0; t < 8; ++t) {
    int c = t * 16 + col;
    float bb = b2[c];
#pragma unroll
    for (int r = 0; r < 4; ++r)
      L[hrow + kg * 4 + r][c] = f2bf(elu(acc2[t][r] + bb));
  }
  {
    int r0 = lane >> 4, seg = lane & 15;
#pragma unroll
    for (int rr = 0; rr < 16; rr += 4) {
      int row = rr + r0;
      *(float4*)((char*)(out + (size_t)(strip * 16 + row) * HD) + seg * 16) =
          *(const float4*)((const char*)&L[hrow + row][0] + seg * 16);
    }
  }
}

// ------- layer-3 MLP + head: 4 chained GEMMs, all B staged in LDS ----------
__global__ __launch_bounds__(256) void mlp3_head(
    const u16* __restrict__ A, const u16* __restrict__ W1t,
    const float* __restrict__ b1, const float* __restrict__ g,
    const float* __restrict__ bt, const float* __restrict__ mu,
    const float* __restrict__ vr, const u16* __restrict__ W2t,
    const float* __restrict__ b2, const u16* __restrict__ L1t,
    const float* __restrict__ lb1, const u16* __restrict__ L2t,
    const float* __restrict__ lb2, float* __restrict__ out) {
  constexpr int PK = HD + 8;
  __shared__ u16 L[192][PK];

  const int tid = threadIdx.x;
  const int wv = tid >> 6, lane = tid & 63;
  const int col = lane & 15, kg = lane >> 4;

#pragma unroll
  for (int t = tid; t < 128 * 16; t += 256) {
    int r = t >> 4, c8 = t & 15;
    *(bf16x8*)&L[r][c8 * 8] = *(const bf16x8*)(W1t + (size_t)r * HD + c8 * 8);
  }
  __syncthreads();

  const int strip = blockIdx.x * 4 + wv;
  const u16* Arow = A + (size_t)(strip * 16 + col) * HD;
  const int hrow = 128 + wv * 16;

  // GEMM1 (BN+ELU)
  f32x4 acc[8];
#pragma unroll
  for (int t = 0; t < 8; ++t) acc[t] = (f32x4){0.f, 0.f, 0.f, 0.f};
#pragma unroll
  for (int kk = 0; kk < HD; kk += 32) {
    bf16x8 av = *(const bf16x8*)(Arow + kk + kg * 8);
#pragma unroll
    for (int t = 0; t < 8; ++t) {
      bf16x8 bv = *(const bf16x8*)&L[t * 16 + col][kk + kg * 8];
      acc[t] = __builtin_amdgcn_mfma_f32_16x16x32_bf16(av, bv, acc[t], 0, 0, 0);
    }
  }
  __syncthreads();
#pragma unroll
  for (int t = tid; t < 128 * 16; t += 256) {   // stage W2
    int r = t >> 4, c8 = t & 15;
    *(bf16x8*)&L[r][c8 * 8] = *(const bf16x8*)(W2t + (size_t)r * HD + c8 * 8);
  }
#pragma unroll
  for (int t = 0; t < 8; ++t) {
    int c = t * 16 + col;
    float rs = rsqrtf(vr[c] + BN_EPS) * g[c];
    float bb = bt[c] + (b1[c] - mu[c]) * rs;
#pragma unroll
    for (int r = 0; r < 4; ++r)
      L[hrow + kg * 4 + r][c] = f2bf(elu(acc[t][r] * rs + bb));
  }
  __syncthreads();

  // GEMM2 (+b2, ELU)
#pragma unroll
  for (int t = 0; t < 8; ++t) acc[t] = (f32x4){0.f, 0.f, 0.f, 0.f};
#pragma unroll
  for (int kk = 0; kk < HD; kk += 32) {
    bf16x8 av = *(const bf16x8*)&L[hrow + col][kk + kg * 8];
#pragma unroll
    for (int t = 0; t < 8; ++t) {
      bf16x8 bv = *(const bf16x8*)&L[t * 16 + col][kk + kg * 8];
      acc[t] = __builtin_amdgcn_mfma_f32_16x16x32_bf16(av, bv, acc[t], 0, 0, 0);
    }
  }
  __syncthreads();
#pragma unroll
  for (int t = tid; t < 128 * 16; t += 256) {   // stage lin1
    int r = t >> 4, c8 = t & 15;
    *(bf16x8*)&L[r][c8 * 8] = *(const bf16x8*)(L1t + (size_t)r * HD + c8 * 8);
  }
#pragma unroll
  for (int t = 0; t < 8; ++t) {
    int c = t * 16 + col;
    float bb = b2[c];
#pragma unroll
    for (int r = 0; r < 4; ++r)
      L[hrow + kg * 4 + r][c] = f2bf(elu(acc[t][r] + bb));
  }
  __syncthreads();

  // LIN1 (+lb1, ELU)
#pragma unroll
  for (int t = 0; t < 8; ++t) acc[t] = (f32x4){0.f, 0.f, 0.f, 0.f};
#pragma unroll
  for (int kk = 0; kk < HD; kk += 32) {
    bf16x8 av = *(const bf16x8*)&L[hrow + col][kk + kg * 8];
#pragma unroll
    for (int t = 0; t < 8; ++t) {
      bf16x8 bv = *(const bf16x8*)&L[t * 16 + col][kk + kg * 8];
      acc[t] = __builtin_amdgcn_mfma_f32_16x16x32_bf16(av, bv, acc[t], 0, 0, 0);
    }
  }
  __syncthreads();
#pragma unroll
  for (int t = tid; t < 64 * 16; t += 256) {    // stage lin2 (64 rows)
    int r = t >> 4, c8 = t & 15;
    *(bf16x8*)&L[r][c8 * 8] = *(const bf16x8*)(L2t + (size_t)r * HD + c8 * 8);
  }
#pragma unroll
  for (int t = 0; t < 8; ++t) {
    int c = t * 16 + col;
    float bb = lb1[c];
#pragma unroll
    for (int r = 0; r < 4; ++r)
      L[hrow + kg * 4 + r][c] = f2bf(elu(acc[t][r] + bb));
  }
  __syncthreads();

  // LIN2 (+lb2) -> fp32 out [.][64]
  f32x4 acc2[4];
#pragma unroll
  for (int t = 0; t < 4; ++t) acc2[t] = (f32x4){0.f, 0.f, 0.f, 0.f};
#pragma unroll
  for (int kk = 0; kk < HD; kk += 32) {
    bf16x8 av = *(const bf16x8*)&L[hrow + col][kk + kg * 8];
#pragma unroll
    for (int t = 0; t < 4; ++t) {
      bf16x8 bv = *(const bf16x8*)&L[t * 16 + col][kk + kg * 8];
      acc2[t] = __builtin_amdgcn_mfma_f32_16x16x32_bf16(av, bv, acc2[t], 0, 0, 0);
    }
  }
#pragma unroll
  for (int t = 0; t < 4; ++t) {
    int c = t * 16 + col;
    float bb = lb2[c];
#pragma unroll
    for (int r = 0; r < 4; ++r)
      ((float*)&L[hrow + kg * 4 + r][0])[c] = acc2[t][r] + bb;
  }
  {
    int r0 = lane >> 4, seg = lane & 15;
#pragma unroll
    for (int rr = 0; rr < 16; rr += 4) {
      int row = rr + r0;
      *(float4*)((char*)(out + (size_t)(strip * 16 + row) * 64) + seg * 16) =
          *(const float4*)((const char*)&L[hrow + row][0] + seg * 16);
    }
  }
}

extern "C" void kernel_launch(void* const* d_in, const int* in_sizes, int n_in,
                              void* d_out, int out_size, void* d_ws, size_t ws_size,
                              hipStream_t stream) {
  const float* x = (const float*)d_in[0];
  const int* ei  = (const int*)d_in[1];
  const float* p[30];
  for (int i = 0; i < 30 && i < n_in; ++i) p[i] = (const float*)d_in[i];

  const size_t FEAT = (size_t)NODES * HD;
  u16* xb   = (u16*)d_ws;
  u16* tmp  = xb + FEAT;
  u16* wt   = tmp + FEAT;
  u16* wts[8];
  for (int m = 0; m < 8; ++m) wts[m] = wt + (size_t)m * HD * HD;
  int* cnt    = (int*)(wt + 8 * HD * HD);
  int* bucket = cnt + NODES;

  dim3 blk(256);
  const int edgeGrid = (EDGES + 255) / 256;   // 2344
  const int gathGrid = NODES / 8;             // 5000
  const int gemmGrid = NODES / 64;            // 625

  WPrep wp;
  const int widx[8] = {2, 8, 10, 16, 18, 24, 26, 28};
  for (int m = 0; m < 8; ++m) { wp.s[m] = p[widx[m]]; wp.d[m] = wts[m]; }
  prep_all<<<5285, blk, 0, stream>>>((const float4*)x, (ushort4*)xb, wp, cnt);
  bucket_fill<<<edgeGrid, blk, 0, stream>>>(ei, cnt, bucket);

  for (int l = 0; l < 2; ++l) {
    const int base = 2 + l * 8;
    gather_w<<<gathGrid, blk, 0, stream>>>(xb, cnt, bucket, tmp);
    mlp_fused<<<gemmGrid, blk, 0, stream>>>(
        tmp, wts[l * 2], p[base + 1], p[base + 2], p[base + 3], p[base + 4],
        p[base + 5], wts[l * 2 + 1], p[base + 7], xb);
  }
  gather_w<<<gathGrid, blk, 0, stream>>>(xb, cnt, bucket, tmp);
  mlp3_head<<<gemmGrid, blk, 0, stream>>>(
      tmp, wts[4], p[19], p[20], p[21], p[22], p[23], wts[5], p[25],
      wts[6], p[27], wts[7], p[29], (float*)d_out);
}